// Round 1
// baseline (297.852 us; speedup 1.0000x reference)
//
#include <hip/hip_runtime.h>
#include <hip/hip_fp16.h>
#include <math.h>

typedef _Float16 f16;
typedef _Float16 f16x8 __attribute__((ext_vector_type(8)));
typedef _Float16 f16x4 __attribute__((ext_vector_type(4)));
typedef float    f32x4 __attribute__((ext_vector_type(4)));

#define MFMA16(a,b,c) __builtin_amdgcn_mfma_f32_16x16x32_f16(a, b, c, 0, 0, 0)

// NEG fill value; -2^32+1 rounds to -2^32 in fp32, matching JAX's where() result.
#define NEGV (-4294967296.0f)

// ---------------------------------------------------------------------------
// Kernel 1: QKV projection.  out[m,c] = sum_k x[m,k] * W[c,k] + b[c]
// x: [8192,512] f32.  Q,K written natural f16 [8192][512]; V written
// transposed f16 [(h*4+b)*64+d][2048] for the attention PV step.
// Tile 128x64, 4 waves (2x2), BK=32 (one f16 MFMA K-step).
// ---------------------------------------------------------------------------
__global__ __launch_bounds__(256) void qkv_gemm(
    const float* __restrict__ x,
    const float* __restrict__ Wq, const float* __restrict__ bq,
    const float* __restrict__ Wk, const float* __restrict__ bk,
    const float* __restrict__ Wv, const float* __restrict__ bv,
    f16* __restrict__ Qws, f16* __restrict__ Kws, f16* __restrict__ Vt)
{
    __shared__ f16 Al[128 * 48];   // stride 48 f16 = 96B (16B aligned rows)
    __shared__ f16 Wl[64 * 48];

    const int tid = threadIdx.x;
    const int bx  = blockIdx.x;          // 0..23 (3 weights x 8 n-tiles)
    const int m0  = blockIdx.y * 128;
    const int widx = bx >> 3;            // 0=Q 1=K 2=V
    const int n0   = (bx & 7) * 64;

    const float* W    = (widx == 0) ? Wq : (widx == 1) ? Wk : Wv;
    const float* bias = (widx == 0) ? bq : (widx == 1) ? bk : bv;

    const int wid = tid >> 6, lane = tid & 63;
    const int g = lane >> 4, c = lane & 15;
    const int wm = (wid >> 1) * 64, wn = (wid & 1) * 32;

    const int sr = tid >> 3, sc = tid & 7;   // staging: 32 rows x 8 float4-chunks

    f32x4 acc[4][2] = {};

    for (int kk = 0; kk < 512; kk += 32) {
        __syncthreads();
        #pragma unroll
        for (int rr = 0; rr < 4; ++rr) {            // A: 128 rows x 32 k
            int row = sr + rr * 32;
            float4 v = *(const float4*)&x[(size_t)(m0 + row) * 512 + kk + sc * 4];
            f16x4 h4 = {(f16)v.x, (f16)v.y, (f16)v.z, (f16)v.w};
            *(f16x4*)&Al[row * 48 + sc * 4] = h4;
        }
        #pragma unroll
        for (int rr = 0; rr < 2; ++rr) {            // W: 64 rows x 32 k
            int row = sr + rr * 32;
            float4 v = *(const float4*)&W[(size_t)(n0 + row) * 512 + kk + sc * 4];
            f16x4 h4 = {(f16)v.x, (f16)v.y, (f16)v.z, (f16)v.w};
            *(f16x4*)&Wl[row * 48 + sc * 4] = h4;
        }
        __syncthreads();

        // B-frag: lane -> W[n=c, k=g*8+j] (natural [n][k] LDS rows)
        f16x8 b0 = *(const f16x8*)&Wl[(wn +  0 + c) * 48 + g * 8];
        f16x8 b1 = *(const f16x8*)&Wl[(wn + 16 + c) * 48 + g * 8];
        #pragma unroll
        for (int mf = 0; mf < 4; ++mf) {
            f16x8 a = *(const f16x8*)&Al[(wm + mf * 16 + c) * 48 + g * 8];
            acc[mf][0] = MFMA16(a, b0, acc[mf][0]);
            acc[mf][1] = MFMA16(a, b1, acc[mf][1]);
        }
    }

    // Epilogue. C/D layout: col = c (lane&15), row = g*4 + reg.
    #pragma unroll
    for (int nf = 0; nf < 2; ++nf) {
        int cc = n0 + wn + nf * 16 + c;      // output channel within this matrix
        float bval = bias[cc];
        #pragma unroll
        for (int mf = 0; mf < 4; ++mf) {
            if (widx < 2) {
                f16* outp = (widx == 0) ? Qws : Kws;
                #pragma unroll
                for (int r = 0; r < 4; ++r) {
                    int mrow = m0 + wm + mf * 16 + g * 4 + r;
                    outp[(size_t)mrow * 512 + cc] = (f16)(acc[mf][nf][r] + bval);
                }
            } else {
                // V transposed: row = n*64+d, col = t  (n = h*4+b)
                int h  = n0 >> 6;
                int d  = wn + nf * 16 + c;
                int t0 = m0 + wm + mf * 16 + g * 4;    // global m, mult of 4
                int b  = t0 >> 11;
                int ts = t0 & 2047;
                int nn = h * 4 + b;
                f16x4 pk = {(f16)(acc[mf][nf][0] + bval), (f16)(acc[mf][nf][1] + bval),
                            (f16)(acc[mf][nf][2] + bval), (f16)(acc[mf][nf][3] + bval)};
                *(f16x4*)&Vt[((size_t)(nn * 64 + d)) * 2048 + ts] = pk;
            }
        }
    }
}

// ---------------------------------------------------------------------------
// Kernel 2: fused attention.  One block = one (n = h*4+b) x 128 q-rows.
// 4 waves, each owns 32 q-rows.  Loops 32 tiles of 64 keys:
//   S = Q Kt /8 (MFMA) -> write pre_score (unmasked, nontemporal)
//   -> causal+padding mask (quirk: pm batch = n>>3) -> online softmax
//   -> P via per-wave LDS transpose -> O += P V (MFMA).
// ---------------------------------------------------------------------------
__global__ __launch_bounds__(256) void attn_kernel(
    const f16* __restrict__ Qws, const f16* __restrict__ Kws,
    const f16* __restrict__ Vt,  const int* __restrict__ pmask,
    float* __restrict__ pre_score, f16* __restrict__ attn_out)
{
    __shared__ f16 Kl[64 * 72];        // [t][d], stride 72 f16 = 144B
    __shared__ f16 Vl[64 * 72];        // [d][t]
    __shared__ f16 Pl[4][32 * 72];     // per-wave [q][t]

    const int tid = threadIdx.x;
    const int wid = tid >> 6, lane = tid & 63;
    const int g = lane >> 4, c = lane & 15;
    const int qt = blockIdx.x;         // 0..15
    const int n  = blockIdx.y;         // 0..31  (= h*4 + b)
    const int h = n >> 2, b = n & 3;
    const int pmrow = n >> 3;          // the reference's ordering quirk
    const int q0 = qt * 128 + wid * 32;

    // Q fragments in registers (A-op: lane -> Q[q=c, k=g*8+j])
    f16x8 qf[2][2];
    #pragma unroll
    for (int mi = 0; mi < 2; ++mi)
        #pragma unroll
        for (int ks = 0; ks < 2; ++ks)
            qf[mi][ks] = *(const f16x8*)
                &Qws[(size_t)(b * 2048 + q0 + mi * 16 + c) * 512 + h * 64 + ks * 32 + g * 8];

    f32x4 o[2][4] = {};
    float mrow[2][4], lrow[2][4];
    #pragma unroll
    for (int mi = 0; mi < 2; ++mi)
        #pragma unroll
        for (int r = 0; r < 4; ++r) { mrow[mi][r] = -INFINITY; lrow[mi][r] = 0.0f; }

    const int sr = tid >> 3, sc = tid & 7;

    for (int kt = 0; kt < 32; ++kt) {
        __syncthreads();
        #pragma unroll
        for (int rr = 0; rr < 2; ++rr) {
            int row = sr + rr * 32;
            *(uint4*)&Kl[row * 72 + sc * 8] =
                *(const uint4*)&Kws[(size_t)(b * 2048 + kt * 64 + row) * 512 + h * 64 + sc * 8];
            *(uint4*)&Vl[row * 72 + sc * 8] =
                *(const uint4*)&Vt[(size_t)(n * 64 + row) * 2048 + kt * 64 + sc * 8];
        }
        __syncthreads();

        // ---- S = Q K^T -------------------------------------------------
        f32x4 s[2][4] = {};
        #pragma unroll
        for (int nf = 0; nf < 4; ++nf) {
            #pragma unroll
            for (int ks = 0; ks < 2; ++ks) {
                f16x8 kf = *(const f16x8*)&Kl[(nf * 16 + c) * 72 + ks * 32 + g * 8];
                s[0][nf] = MFMA16(qf[0][ks], kf, s[0][nf]);
                s[1][nf] = MFMA16(qf[1][ks], kf, s[1][nf]);
            }
        }

        // ---- scale, emit pre_score, mask -------------------------------
        #pragma unroll
        for (int nf = 0; nf < 4; ++nf) {
            int tg  = kt * 64 + nf * 16 + c;
            int pmv = pmask[pmrow * 2048 + tg];
            #pragma unroll
            for (int mi = 0; mi < 2; ++mi) {
                #pragma unroll
                for (int r = 0; r < 4; ++r) {
                    float v = s[mi][nf][r] * 0.125f;
                    int srow = qt * 128 + wid * 32 + mi * 16 + g * 4 + r;
                    __builtin_nontemporal_store(
                        v, &pre_score[((size_t)n * 2048 + srow) * 2048 + tg]);
                    s[mi][nf][r] = (tg <= srow && pmv != 0) ? v : NEGV;
                }
            }
        }

        // ---- online softmax --------------------------------------------
        float alpha[2][4];
        #pragma unroll
        for (int mi = 0; mi < 2; ++mi) {
            #pragma unroll
            for (int r = 0; r < 4; ++r) {
                float rm = fmaxf(fmaxf(s[mi][0][r], s[mi][1][r]),
                                 fmaxf(s[mi][2][r], s[mi][3][r]));
                rm = fmaxf(rm, __shfl_xor(rm, 1, 64));
                rm = fmaxf(rm, __shfl_xor(rm, 2, 64));
                rm = fmaxf(rm, __shfl_xor(rm, 4, 64));
                rm = fmaxf(rm, __shfl_xor(rm, 8, 64));
                float mn = fmaxf(mrow[mi][r], rm);
                alpha[mi][r] = __expf(mrow[mi][r] - mn);   // exp(-inf)=0 on 1st tile
                mrow[mi][r] = mn;
            }
        }
        #pragma unroll
        for (int mi = 0; mi < 2; ++mi) {
            float rs[4] = {0.f, 0.f, 0.f, 0.f};
            #pragma unroll
            for (int nf = 0; nf < 4; ++nf) {
                #pragma unroll
                for (int r = 0; r < 4; ++r) {
                    float p = __expf(s[mi][nf][r] - mrow[mi][r]);
                    rs[r] += p;
                    Pl[wid][(mi * 16 + g * 4 + r) * 72 + nf * 16 + c] = (f16)p;
                }
            }
            #pragma unroll
            for (int r = 0; r < 4; ++r) {
                float t = rs[r];
                t += __shfl_xor(t, 1, 64);
                t += __shfl_xor(t, 2, 64);
                t += __shfl_xor(t, 4, 64);
                t += __shfl_xor(t, 8, 64);
                lrow[mi][r] = lrow[mi][r] * alpha[mi][r] + t;
                #pragma unroll
                for (int dn = 0; dn < 4; ++dn) o[mi][dn][r] *= alpha[mi][r];
            }
        }
        __syncthreads();   // bulletproof ordering of Pl cross-lane write->read

        // ---- O += P V  (A = P from Pl, B = V from Vl[d][t]) -------------
        #pragma unroll
        for (int ks = 0; ks < 2; ++ks) {
            f16x8 pa0 = *(const f16x8*)&Pl[wid][( 0 + c) * 72 + ks * 32 + g * 8];
            f16x8 pa1 = *(const f16x8*)&Pl[wid][(16 + c) * 72 + ks * 32 + g * 8];
            #pragma unroll
            for (int dn = 0; dn < 4; ++dn) {
                f16x8 vb = *(const f16x8*)&Vl[(dn * 16 + c) * 72 + ks * 32 + g * 8];
                o[0][dn] = MFMA16(pa0, vb, o[0][dn]);
                o[1][dn] = MFMA16(pa1, vb, o[1][dn]);
            }
        }
    }

    // ---- epilogue: O /= l, write heads f16 [b*2048+s][h*64+d] -----------
    #pragma unroll
    for (int mi = 0; mi < 2; ++mi)
        #pragma unroll
        for (int dn = 0; dn < 4; ++dn)
            #pragma unroll
            for (int r = 0; r < 4; ++r) {
                int srow = qt * 128 + wid * 32 + mi * 16 + g * 4 + r;
                attn_out[(size_t)(b * 2048 + srow) * 512 + h * 64 + dn * 16 + c] =
                    (f16)(o[mi][dn][r] / lrow[mi][r]);
            }
}

// ---------------------------------------------------------------------------
// Kernel 3: output projection.  out[m,n] = sum_c heads[m,c]*Wo[n,c] + bo[n]
// heads f16 [8192][512], Wo f32 [512][512], out f32 -> d_out[0:4194304).
// ---------------------------------------------------------------------------
__global__ __launch_bounds__(256) void out_gemm(
    const f16* __restrict__ Aattn, const float* __restrict__ Wo,
    const float* __restrict__ bo, float* __restrict__ outp)
{
    __shared__ f16 Al[128 * 48];
    __shared__ f16 Wl[64 * 48];

    const int tid = threadIdx.x;
    const int n0 = blockIdx.x * 64;
    const int m0 = blockIdx.y * 128;
    const int wid = tid >> 6, lane = tid & 63;
    const int g = lane >> 4, c = lane & 15;
    const int wm = (wid >> 1) * 64, wn = (wid & 1) * 32;

    const int sr4 = tid >> 2, sc4 = tid & 3;   // A: 64 rows x 4 16B-chunks
    const int sr8 = tid >> 3, sc8 = tid & 7;   // W: 32 rows x 8 float4-chunks

    f32x4 acc[4][2] = {};

    for (int kk = 0; kk < 512; kk += 32) {
        __syncthreads();
        #pragma unroll
        for (int rr = 0; rr < 2; ++rr) {
            int row = sr4 + rr * 64;
            *(uint4*)&Al[row * 48 + sc4 * 8] =
                *(const uint4*)&Aattn[(size_t)(m0 + row) * 512 + kk + sc4 * 8];
        }
        #pragma unroll
        for (int rr = 0; rr < 2; ++rr) {
            int row = sr8 + rr * 32;
            float4 v = *(const float4*)&Wo[(size_t)(n0 + row) * 512 + kk + sc8 * 4];
            f16x4 h4 = {(f16)v.x, (f16)v.y, (f16)v.z, (f16)v.w};
            *(f16x4*)&Wl[row * 48 + sc8 * 4] = h4;
        }
        __syncthreads();

        f16x8 b0 = *(const f16x8*)&Wl[(wn +  0 + c) * 48 + g * 8];
        f16x8 b1 = *(const f16x8*)&Wl[(wn + 16 + c) * 48 + g * 8];
        #pragma unroll
        for (int mf = 0; mf < 4; ++mf) {
            f16x8 a = *(const f16x8*)&Al[(wm + mf * 16 + c) * 48 + g * 8];
            acc[mf][0] = MFMA16(a, b0, acc[mf][0]);
            acc[mf][1] = MFMA16(a, b1, acc[mf][1]);
        }
    }

    #pragma unroll
    for (int nf = 0; nf < 2; ++nf) {
        int cc = n0 + wn + nf * 16 + c;
        float bval = bo[cc];
        #pragma unroll
        for (int mf = 0; mf < 4; ++mf)
            #pragma unroll
            for (int r = 0; r < 4; ++r)
                outp[(size_t)(m0 + wm + mf * 16 + g * 4 + r) * 512 + cc] =
                    acc[mf][nf][r] + bval;
    }
}

// ---------------------------------------------------------------------------
extern "C" void kernel_launch(void* const* d_in, const int* in_sizes, int n_in,
                              void* d_out, int out_size, void* d_ws, size_t ws_size,
                              hipStream_t stream)
{
    (void)in_sizes; (void)n_in; (void)out_size; (void)ws_size;

    const float* x  = (const float*)d_in[0];
    const int*   pm = (const int*)  d_in[1];
    const float* Wq = (const float*)d_in[2];
    const float* bq = (const float*)d_in[3];
    const float* Wk = (const float*)d_in[4];
    const float* bk = (const float*)d_in[5];
    const float* Wv = (const float*)d_in[6];
    const float* bv = (const float*)d_in[7];
    const float* Wo = (const float*)d_in[8];
    const float* bo = (const float*)d_in[9];

    float* out = (float*)d_out;                 // [4][2048][512]
    float* pre = out + (size_t)4 * 2048 * 512;  // [32][2048][2048]

    f16* Qws  = (f16*)d_ws;                     //  8 MiB
    f16* Kws  = Qws + (size_t)8192 * 512;       //  8 MiB
    f16* Vt   = Kws + (size_t)8192 * 512;       //  8 MiB (transposed V)
    f16* Aat  = Vt  + (size_t)2048 * 2048;      //  8 MiB (heads)

    qkv_gemm  <<<dim3(24, 64), 256, 0, stream>>>(x, Wq, bq, Wk, bk, Wv, bv, Qws, Kws, Vt);
    attn_kernel<<<dim3(16, 32), 256, 0, stream>>>(Qws, Kws, Vt, pm, pre, Aat);
    out_gemm  <<<dim3(8, 64),  256, 0, stream>>>(Aat, Wo, bo, out);
}